// Round 5
// baseline (22615.408 us; speedup 1.0000x reference)
//
#include <hip/hip_runtime.h>

typedef unsigned int  u32;
typedef unsigned short u16;
typedef float v2f __attribute__((ext_vector_type(2)));

// B=8, NS=80, NN=81, H=256, L=2, STEPS=8, VOCAB=30000
#define ROWS 648          // B*NN

__device__ __forceinline__ float sigf(float x){ return 1.0f/(1.0f+__expf(-x)); }
__device__ __forceinline__ float tanh_fast(float x){
  float e = __expf(-2.0f*fabsf(x));
  float r = (1.0f-e)/(1.0f+e);
  return copysignf(r,x);
}
__device__ __forceinline__ u16 f2bf(float f){        // RTNE f32->bf16
  u32 u = __float_as_uint(f);
  u += 0x7FFFu + ((u>>16)&1u);
  return (u16)(u>>16);
}
__device__ __forceinline__ u32 packbf2(float lo, float hi){
  return (u32)f2bf(lo) | ((u32)f2bf(hi)<<16);
}
__device__ __forceinline__ float bf2f(u16 v){ return __uint_as_float(((u32)v)<<16); }
__device__ __forceinline__ float bflo(u32 u){ return __uint_as_float(u<<16); }
__device__ __forceinline__ float bfhi(u32 u){ return __uint_as_float(u & 0xFFFF0000u); }
__device__ __forceinline__ v2f unpk(u32 w){
  v2f r; r.x = bflo(w); r.y = bfhi(w); return r;
}

// ---------------- weight packing ----------------------------------------
// gate-quad, k-pair layout: dst[k2*1024 + j*4 + g] = pack(src[2k2][g*256+j], src[2k2+1][g*256+j])
__global__ void pack_gates(const float* __restrict__ A, const float* __restrict__ Bm,
                           u32* __restrict__ dst, int Krows){
  int id = blockIdx.x*256 + threadIdx.x;
  int tot = (Krows>>1)*1024;
  if (id >= tot) return;
  int k2 = id >> 10;
  int c  = id & 1023;
  int j = c >> 2, g = c & 3;
  int k0 = 2*k2, k1 = 2*k2+1;
  float v0 = (k0<256) ? A[k0*1024 + g*256 + j] : Bm[(k0-256)*1024 + g*256 + j];
  float v1 = (k1<256) ? A[k1*1024 + g*256 + j] : Bm[(k1-256)*1024 + g*256 + j];
  dst[id] = packbf2(v0, v1);
}

__global__ void pack_pairs(const float* __restrict__ src, u32* __restrict__ dst,
                           int Kpairs, int ncol){
  int id = blockIdx.x*256 + threadIdx.x;
  if (id >= Kpairs*ncol) return;
  int k2 = id / ncol, j = id - k2*ncol;
  dst[id] = packbf2(src[(2*k2)*ncol + j], src[(2*k2+1)*ncol + j]);
}

__global__ void k_init_p(float* __restrict__ p0){
  int i = blockIdx.x*256 + threadIdx.x;
  if (i < ROWS) p0[i] = ((i % 81)==0) ? 1.0f : 0.0f;
}

// ---------------- K1: statement embedder + X0 precompute ----------------
__global__ __launch_bounds__(512) void k_stmt_x0(
    const float* __restrict__ ne, const float* __restrict__ stWx, const float* __restrict__ stb,
    const float* __restrict__ skWx, const float* __restrict__ skb, float4* __restrict__ X0){
  __shared__ float xv[2][256];
  __shared__ float hv[2][256];
  int r = threadIdx.x >> 8, j = threadIdx.x & 255;
  int bn = blockIdx.x*2 + r;                    // 0..639
  xv[r][j] = ne[bn*256 + j];
  __syncthreads();
  float a0=stb[j], a2=stb[512+j], a3=stb[768+j];
  for (int k=0;k<256;k++){
    float x = xv[r][k];
    const float* w = stWx + k*1024;
    a0 = fmaf(x, w[j], a0); a2 = fmaf(x, w[512+j], a2); a3 = fmaf(x, w[768+j], a3);
  }
  float c = sigf(a0)*tanh_fast(a2);
  float h = sigf(a3)*tanh_fast(c);
  hv[r][j] = h;
  __syncthreads();
  a0=stb[1024+j]; a2=stb[1536+j]; a3=stb[1792+j];
  const float* W1 = stWx + 256*1024;
  for (int k=0;k<256;k++){
    float x = hv[r][k];
    const float* w = W1 + k*1024;
    a0 = fmaf(x, w[j], a0); a2 = fmaf(x, w[512+j], a2); a3 = fmaf(x, w[768+j], a3);
  }
  c = sigf(a0)*tanh_fast(a2);
  h = sigf(a3)*tanh_fast(c);
  __syncthreads();
  xv[r][j] = h;           // stmt row
  __syncthreads();
  float b0=skb[j], b1g=skb[256+j], b2=skb[512+j], b3=skb[768+j];
  for (int k=0;k<256;k++){
    float x = xv[r][k];
    const float* w = skWx + k*1024;
    b0 = fmaf(x, w[j], b0);     b1g = fmaf(x, w[256+j], b1g);
    b2 = fmaf(x, w[512+j], b2); b3 = fmaf(x, w[768+j], b3);
  }
  X0[bn*256 + j] = make_float4(b0,b1g,b2,b3);
}

// ---------------- K3: skip-encoder chains (v3: register-resident W) ------
// One block per chain (s,b); 1024 threads = 4 k-slices (kh) x 256 j.
// Thread (kh,j) holds its W0/W1 column slice in VGPRs (384 regs) — loaded
// ONCE, reused for all 80 steps: zero per-step global weight traffic.
// Cell+LN phases run on threads tid<256 (j role). Blocks are fully
// independent; grid ordered s-ascending so longest chains start first.
__global__ __launch_bounds__(1024, 4) void k_skip_chains(
    const float4* __restrict__ X0,
    const uint4* __restrict__ W0, const uint4* __restrict__ W1,
    const float* __restrict__ skb, const float* __restrict__ lnS, const float* __restrict__ lnB,
    float* __restrict__ skip){
  int chain = blockIdx.x;           // 0..639
  int s = chain >> 3;               // 0..79 ascending
  int b = chain & 7;
  int tid = threadIdx.x;
  int kh = tid >> 8, j = tid & 255;
  // ---- preload weight slices into registers (the whole point) ----
  uint4 w0r[32];
  #pragma unroll
  for (int i=0;i<32;i++) w0r[i] = W0[(kh*32+i)*256 + j];
  uint4 w1r[64];
  #pragma unroll
  for (int i=0;i<64;i++) w1r[i] = W1[(kh*64+i)*256 + j];
  __shared__ float part[16*256];     // [(kh*4+g)][j] gate partials, 16KB
  __shared__ float h0buf[256];       // LN'd h0 (layer0 recurrent input)
  __shared__ float in1buf[512];      // [h0_raw | h1_ln] (layer1 input)
  __shared__ float red[8];
  for (int i=tid; i<256; i+=1024) h0buf[i]=0.f;
  for (int i=tid; i<512; i+=1024) in1buf[i]=0.f;
  float c0=0.f, c1=0.f;
  float s1b0=0,s1b1=0,s1b2=0,s1b3=0, lS0=0,lS1=0,lS2=0,lS3=0, lB0=0,lB1=0,lB2=0,lB3=0;
  if (tid < 256){
    s1b0=skb[1024+j]; s1b1=skb[1280+j]; s1b2=skb[1536+j]; s1b3=skb[1792+j];
    lS0=lnS[j]; lS1=lnS[256+j]; lS2=lnS[512+j]; lS3=lnS[768+j];
    lB0=lnB[j]; lB1=lnB[256+j]; lB2=lnB[512+j]; lB3=lnB[768+j];
  }
  __syncthreads();
  for (int idx=s; idx<80; idx++){
    float4 gx;
    if (tid < 256) gx = X0[(b*80+idx)*256 + j];   // issue early, used after barrier
    // ---- layer0 matvec: h0 @ Wh0 (k2 slice kh*32..+32), weights from regs
    {
      v2f a0={0,0}, a1={0,0}, a2={0,0}, a3={0,0};
      #pragma unroll
      for (int i=0;i<32;i++){
        v2f hp = *(const v2f*)&h0buf[(kh*32+i)*2];
        uint4 w = w0r[i];
        a0 += hp*unpk(w.x); a1 += hp*unpk(w.y);
        a2 += hp*unpk(w.z); a3 += hp*unpk(w.w);
      }
      part[(kh*4+0)*256+j] = a0.x+a0.y;
      part[(kh*4+1)*256+j] = a1.x+a1.y;
      part[(kh*4+2)*256+j] = a2.x+a2.y;
      part[(kh*4+3)*256+j] = a3.x+a3.y;
    }
    __syncthreads();
    // ---- layer0 cell (threads j)
    if (tid < 256){
      float a0=gx.x, a1=gx.y, a2=gx.z, a3=gx.w;   // X0 includes sk_b0
      #pragma unroll
      for (int k=0;k<4;k++){
        a0 += part[(k*4+0)*256+j];
        a1 += part[(k*4+1)*256+j];
        a2 += part[(k*4+2)*256+j];
        a3 += part[(k*4+3)*256+j];
      }
      float ii=sigf(a0), ff=sigf(a1), gg=tanh_fast(a2), oo=sigf(a3);
      c0 = ff*c0 + ii*gg;
      float h0n = oo*tanh_fast(c0);
      in1buf[j] = h0n;
    }
    __syncthreads();
    // ---- layer1 matvec: [h0_raw|h1_ln] @ [Wx1;Wh1] (k2 slice kh*64..+64)
    {
      v2f a0={0,0}, a1={0,0}, a2={0,0}, a3={0,0};
      #pragma unroll
      for (int i=0;i<64;i++){
        v2f hp = *(const v2f*)&in1buf[(kh*64+i)*2];
        uint4 w = w1r[i];
        a0 += hp*unpk(w.x); a1 += hp*unpk(w.y);
        a2 += hp*unpk(w.z); a3 += hp*unpk(w.w);
      }
      part[(kh*4+0)*256+j] = a0.x+a0.y;
      part[(kh*4+1)*256+j] = a1.x+a1.y;
      part[(kh*4+2)*256+j] = a2.x+a2.y;
      part[(kh*4+3)*256+j] = a3.x+a3.y;
    }
    __syncthreads();
    // ---- layer1 cell + skip store + LN stats (threads j)
    float h0n_c=0.f, h1n_c=0.f;
    if (tid < 256){
      float a0=s1b0, a1=s1b1, a2=s1b2, a3=s1b3;
      #pragma unroll
      for (int k=0;k<4;k++){
        a0 += part[(k*4+0)*256+j];
        a1 += part[(k*4+1)*256+j];
        a2 += part[(k*4+2)*256+j];
        a3 += part[(k*4+3)*256+j];
      }
      float ii=sigf(a0), ff=sigf(a1), gg=tanh_fast(a2), oo=sigf(a3);
      c1 = ff*c1 + ii*gg;
      float h1n = oo*tanh_fast(c1);
      skip[((b*81 + s)*81 + (idx+1))*256 + j] = h1n;   // pre-LN output
      h0n_c = in1buf[j]; h1n_c = h1n;
      float sm = c0 + h0n_c + c1 + h1n_c;
      float sq = c0*c0 + h0n_c*h0n_c + c1*c1 + h1n_c*h1n_c;
      #pragma unroll
      for (int off=32; off; off>>=1){ sm += __shfl_xor(sm, off); sq += __shfl_xor(sq, off); }
      if ((j & 63) == 0){ red[j>>6] = sm; red[4+(j>>6)] = sq; }
    }
    __syncthreads();
    // ---- LN apply + publish next-step inputs (threads j)
    if (tid < 256){
      float sm = red[0]+red[1]+red[2]+red[3];
      float sq = red[4]+red[5]+red[6]+red[7];
      float mu = sm * (1.0f/1024.0f);
      float var = sq * (1.0f/1024.0f) - mu*mu;
      float rstd = rsqrtf(var + 1e-6f);
      c0 = (c0 - mu)*rstd*lS0 + lB0;
      float h0ln = (h0n_c - mu)*rstd*lS1 + lB1;
      c1 = (c1 - mu)*rstd*lS2 + lB2;
      float h1ln = (h1n_c - mu)*rstd*lS3 + lB3;
      h0buf[j] = h0ln;
      in1buf[256+j] = h1ln;
    }
    __syncthreads();
  }
}

// ---------------- K4: keys = skip @ ws + bs  (bf16 out) ------------------
__global__ __launch_bounds__(256) void k_keys(const float* __restrict__ skip,
    const u32* __restrict__ wspk, const float* __restrict__ bs, u16* __restrict__ keys){
  __shared__ float skr[8][256];
  int tid = threadIdx.x;
  int bn = blockIdx.x;
  float bsv = bs[tid];
  const float4* sk4 = (const float4*)skip;
  for (int m0=0; m0<81; m0+=8){
    int mc = (81-m0 < 8) ? (81-m0) : 8;
    for (int i=tid; i<mc*64; i+=256){
      int mm = i>>6, kk = i&63;
      float4 v = sk4[(bn*81 + m0 + mm)*64 + kk];
      skr[mm][4*kk+0]=v.x; skr[mm][4*kk+1]=v.y; skr[mm][4*kk+2]=v.z; skr[mm][4*kk+3]=v.w;
    }
    __syncthreads();
    v2f acc[8];
    #pragma unroll
    for (int qq=0;qq<8;qq++) acc[qq]=(v2f){0.f,0.f};
    for (int k2=0;k2<128;k2++){
      v2f w2 = unpk(wspk[k2*256+tid]);
      #pragma unroll
      for (int qq=0;qq<8;qq++){
        v2f sv = *(const v2f*)&skr[qq][2*k2];
        acc[qq] += sv*w2;
      }
    }
    for (int qq=0;qq<mc;qq++) keys[(bn*81+m0+qq)*256+tid] = f2bf(acc[qq].x+acc[qq].y+bsv);
    __syncthreads();
  }
}

// ---------------- Kb: fused q + logits -> softmax -> t -------------------
// mode 0: only m==1; mode 1: m>n || m==80; mode 2: only m==80
__global__ __launch_bounds__(256) void k_attn(
    const float* __restrict__ c0g, const float* __restrict__ h0g,
    const float* __restrict__ c1g, const float* __restrict__ h1g,
    const u32* __restrict__ wkp, const float* __restrict__ bk,
    const u16* __restrict__ keys, const float* __restrict__ w1,
    const float* __restrict__ pcur, float* __restrict__ t, int mode){
  int bn = blockIdx.x; int n = bn % 81;
  int tid = threadIdx.x;
  float pv = pcur[bn];
  if (pv == 0.0f){
    if (tid < 81) t[bn*81 + tid] = 0.0f;
    return;
  }
  __shared__ float hc[1024];
  __shared__ float qv[256];
  __shared__ float lg[81];
  hc[tid]      = c0g[bn*256+tid];
  hc[256+tid]  = h0g[bn*256+tid];
  hc[512+tid]  = c1g[bn*256+tid];
  hc[768+tid]  = h1g[bn*256+tid];
  if (tid < 81) lg[tid] = -3e38f;
  __syncthreads();
  v2f A = {bk[tid], 0.f};
  #pragma unroll 8
  for (int k2=0;k2<512;k2++){
    v2f hp = *(const v2f*)&hc[2*k2];
    A += hp*unpk(wkp[k2*256+tid]);
  }
  qv[tid] = A.x + A.y;
  __syncthreads();
  int lane = tid & 63, wv = tid >> 6;
  float w1v0 = w1[lane], w1v1 = w1[64+lane], w1v2 = w1[128+lane], w1v3 = w1[192+lane];
  for (int m = wv; m < 81; m += 4){
    bool um = (mode==0) ? (m==1) : (mode==2) ? (m==80) : (m>n || m==80);
    if (!um) continue;
    const u16* kr = keys + (bn*81+m)*256;
    float acc;
    acc  = tanh_fast(qv[lane]     + bf2f(kr[lane]))     * w1v0;
    acc += tanh_fast(qv[64+lane]  + bf2f(kr[64+lane]))  * w1v1;
    acc += tanh_fast(qv[128+lane] + bf2f(kr[128+lane])) * w1v2;
    acc += tanh_fast(qv[192+lane] + bf2f(kr[192+lane])) * w1v3;
    #pragma unroll
    for (int off=32; off; off>>=1) acc += __shfl_xor(acc, off);
    if (lane==0) lg[m] = acc;      // b1 omitted: softmax-invariant
  }
  __syncthreads();
  if (tid < 64){
    float v1 = lg[tid];
    float v2 = (tid<17) ? lg[64+tid] : -3e38f;
    float mx = fmaxf(v1, v2);
    #pragma unroll
    for (int off=32; off; off>>=1) mx = fmaxf(mx, __shfl_xor(mx, off));
    float e1 = __expf(v1-mx);
    float e2 = (tid<17) ? __expf(v2-mx) : 0.0f;
    float ssum = e1+e2;
    #pragma unroll
    for (int off=32; off; off>>=1) ssum += __shfl_xor(ssum, off);
    float sc = pv / ssum;
    t[bn*81 + tid] = e1*sc;
    if (tid<17) t[bn*81 + 64+tid] = e2*sc;
  }
}

// ---------------- Kc: x_in/prop einsums + ex-LSTM step + new_p -----------
__global__ __launch_bounds__(1024) void k_update(
    const float* __restrict__ t, const float* __restrict__ skip,
    const float* __restrict__ c0i, const float* __restrict__ h0i,
    const float* __restrict__ c1i, const float* __restrict__ h1i,
    const uint4* __restrict__ WA, const uint4* __restrict__ WB,
    const float* __restrict__ exb,
    float* __restrict__ c0o, float* __restrict__ h0o,
    float* __restrict__ c1o, float* __restrict__ h1o,
    float* __restrict__ pnext){
  int rr = threadIdx.x >> 8, j = threadIdx.x & 255;
  int row = blockIdx.x*4 + rr;
  int b = row / 81, m = row - b*81;
  __shared__ float tcol[4][81];
  __shared__ float xh[4][512];
  if (j < 81) tcol[rr][j] = t[(b*81 + j)*81 + m];
  __syncthreads();
  float xa=0.f, c0p=0.f, h0p=0.f, c1p=0.f, h1p=0.f, ts=0.f;
  for (int n=0;n<81;n++){
    float tv = tcol[rr][n];
    ts += tv;
    if (tv != 0.0f){
      xa  = fmaf(tv, skip[((b*81+n)*81 + m)*256 + j], xa);
      int st = (b*81+n)*256 + j;
      c0p = fmaf(tv, c0i[st], c0p);
      h0p = fmaf(tv, h0i[st], h0p);
      c1p = fmaf(tv, c1i[st], c1p);
      h1p = fmaf(tv, h1i[st], h1p);
    }
  }
  bool alive = (ts != 0.0f);
  float inv = 1.0f/(ts + 1e-7f);
  xa*=inv; c0p*=inv; h0p*=inv; c1p*=inv; h1p*=inv;
  if (j==0) pnext[row] = ts;
  xh[rr][j] = xa; xh[rr][256+j] = h0p;
  __syncthreads();
  float c0n=0.f, h0n=0.f;
  if (alive){
    v2f A0={exb[j],0.f}, A1={exb[256+j],0.f}, A2={exb[512+j],0.f}, A3={exb[768+j],0.f};
    #pragma unroll 8
    for (int k2=0;k2<256;k2++){
      v2f hp = *(const v2f*)&xh[rr][2*k2];
      uint4 w = WA[k2*256+j];
      A0 += hp*unpk(w.x); A1 += hp*unpk(w.y);
      A2 += hp*unpk(w.z); A3 += hp*unpk(w.w);
    }
    float a0=A0.x+A0.y, a1=A1.x+A1.y, a2=A2.x+A2.y, a3=A3.x+A3.y;
    c0n = sigf(a1)*c0p + sigf(a0)*tanh_fast(a2);
    h0n = sigf(a3)*tanh_fast(c0n);
  }
  __syncthreads();
  xh[rr][j] = h0n; xh[rr][256+j] = h1p;
  __syncthreads();
  if (alive){
    v2f A0={exb[1024+j],0.f}, A1={exb[1280+j],0.f}, A2={exb[1536+j],0.f}, A3={exb[1792+j],0.f};
    #pragma unroll 8
    for (int k2=0;k2<256;k2++){
      v2f hp = *(const v2f*)&xh[rr][2*k2];
      uint4 w = WB[k2*256+j];
      A0 += hp*unpk(w.x); A1 += hp*unpk(w.y);
      A2 += hp*unpk(w.z); A3 += hp*unpk(w.w);
    }
    float a0=A0.x+A0.y, a1=A1.x+A1.y, a2=A2.x+A2.y, a3=A3.x+A3.y;
    float c1n = sigf(a1)*c1p + sigf(a0)*tanh_fast(a2);
    float h1n = sigf(a3)*tanh_fast(c1n);
    int o = row*256 + j;
    c0o[o]=c0n; h0o[o]=h0n; c1o[o]=c1n; h1o[o]=h1n;
  }
}

// ---------------- K6: out = h_exit @ wo + bo -----------------------------
__global__ __launch_bounds__(256) void k_out(
    const float* __restrict__ h1f, const int* __restrict__ exitIdx,
    const float* __restrict__ wo, const float* __restrict__ bo, float* __restrict__ out){
  __shared__ float hv[8][256];
  int tid = threadIdx.x;
  for (int i = tid; i < 2048; i += 256){
    int b = i >> 8, k = i & 255;
    hv[b][k] = h1f[(b*81 + exitIdx[b])*256 + k];
  }
  __syncthreads();
  int v = blockIdx.x*256 + tid;
  if (v >= 30000) return;
  float acc[8];
  #pragma unroll
  for (int b=0;b<8;b++) acc[b] = bo[v];
  for (int k=0;k<256;k++){
    float w = wo[k*30000 + v];
    #pragma unroll
    for (int b=0;b<8;b++) acc[b] = fmaf(hv[b][k], w, acc[b]);
  }
  #pragma unroll
  for (int b=0;b<8;b++) out[b*30000+v] = acc[b];
}

// ---------------- launch --------------------------------------------------
extern "C" void kernel_launch(void* const* d_in, const int* in_sizes, int n_in,
                              void* d_out, int out_size, void* d_ws, size_t ws_size,
                              hipStream_t stream){
  (void)in_sizes; (void)n_in; (void)out_size;
  const float* ne    = (const float*)d_in[0];
  const int*   exitI = (const int*)d_in[10];
  const float* stWx  = (const float*)d_in[12];
  const float* stb   = (const float*)d_in[14];
  const float* skWx  = (const float*)d_in[15];
  const float* skWh  = (const float*)d_in[16];
  const float* skb   = (const float*)d_in[17];
  const float* lnS   = (const float*)d_in[18];
  const float* lnB   = (const float*)d_in[19];
  const float* exWx  = (const float*)d_in[20];
  const float* exWh  = (const float*)d_in[21];
  const float* exb   = (const float*)d_in[22];
  const float* wk    = (const float*)d_in[23];
  const float* bk    = (const float*)d_in[24];
  const float* wsm   = (const float*)d_in[25];
  const float* bs    = (const float*)d_in[26];
  const float* w1    = (const float*)d_in[27];
  const float* wo    = (const float*)d_in[29];
  const float* bo    = (const float*)d_in[30];
  float* out = (float*)d_out;

  char* w = (char*)d_ws;
  size_t off = 0;
  auto alloc = [&](size_t bytes)->char*{
    char* p = w + off; off += (bytes + 255) & ~size_t(255); return p;
  };
  float4* X0   = (float4*)alloc((size_t)640*256*16);
  u32* W0pk    = (u32*)alloc((size_t)128*1024*4);
  u32* W1pk    = (u32*)alloc((size_t)256*1024*4);
  u32* WApk    = (u32*)alloc((size_t)256*1024*4);
  u32* WBpk    = (u32*)alloc((size_t)256*1024*4);
  u32* wkp     = (u32*)alloc((size_t)512*256*4);
  u32* wspk    = (u32*)alloc((size_t)128*256*4);
  float* skip  = (float*)alloc((size_t)8*81*81*256*4);   // fp32
  u16* keys    = (u16*)alloc((size_t)8*81*81*256*2);     // bf16
  float* tb    = (float*)alloc((size_t)ROWS*81*4);
  float* p0    = (float*)alloc(ROWS*4);
  float* p1    = (float*)alloc(ROWS*4);
  float* stA   = (float*)alloc((size_t)4*ROWS*256*4);
  float* stB   = (float*)alloc((size_t)4*ROWS*256*4);
  if (off > ws_size) return;   // workspace too small — surfaces as absmax fail

  const size_t ST = (size_t)ROWS*256;
  float *A_c0=stA, *A_h0=stA+ST, *A_c1=stA+2*ST, *A_h1=stA+3*ST;
  float *B_c0=stB, *B_h0=stB+ST, *B_c1=stB+2*ST, *B_h1=stB+3*ST;

  hipMemsetAsync(skip, 0, (size_t)8*81*81*256*4, stream);
  hipMemsetAsync(stA, 0, (size_t)4*ROWS*256*4, stream);
  hipMemsetAsync(stB, 0, (size_t)4*ROWS*256*4, stream);
  k_init_p<<<3,256,0,stream>>>(p0);

  pack_gates<<<512, 256, 0, stream>>>(skWh, skWh, W0pk, 256);                       // Wh0
  pack_gates<<<1024,256, 0, stream>>>(skWx+256*1024, skWh+256*1024, W1pk, 512);     // [Wx1;Wh1]
  pack_gates<<<1024,256, 0, stream>>>(exWx, exWh, WApk, 512);                       // [exWx0;exWh0]
  pack_gates<<<1024,256, 0, stream>>>(exWx+256*1024, exWh+256*1024, WBpk, 512);     // [exWx1;exWh1]
  pack_pairs<<<512, 256, 0, stream>>>(wk, wkp, 512, 256);
  pack_pairs<<<128, 256, 0, stream>>>(wsm, wspk, 128, 256);

  k_stmt_x0<<<320, 512, 0, stream>>>(ne, stWx, stb, skWx, skb, X0);
  k_skip_chains<<<640, 1024, 0, stream>>>(X0, (const uint4*)W0pk, (const uint4*)W1pk,
                                          skb, lnS, lnB, skip);
  k_keys<<<648, 256, 0, stream>>>(skip, wspk, bs, keys);

  float* pc = p0; float* pn = p1;
  for (int s=0; s<8; s++){
    float *ic0,*ih0,*ic1,*ih1,*oc0,*oh0,*oc1,*oh1;
    if ((s & 1) == 0){ ic0=A_c0; ih0=A_h0; ic1=A_c1; ih1=A_h1; oc0=B_c0; oh0=B_h0; oc1=B_c1; oh1=B_h1; }
    else             { ic0=B_c0; ih0=B_h0; ic1=B_c1; ih1=B_h1; oc0=A_c0; oh0=A_h0; oc1=A_c1; oh1=A_h1; }
    int mode = (s==0) ? 0 : ((s==7) ? 2 : 1);
    k_attn<<<648, 256, 0, stream>>>(ic0, ih0, ic1, ih1, wkp, bk, keys, w1, pc, tb, mode);
    k_update<<<162, 1024, 0, stream>>>(tb, skip, ic0, ih0, ic1, ih1,
                                       (const uint4*)WApk, (const uint4*)WBpk, exb,
                                       oc0, oh0, oc1, oh1, pn);
    float* tmp = pc; pc = pn; pn = tmp;
  }
  // final states are in buffer A (step 7 writes A)
  k_out<<<(30000+255)/256, 256, 0, stream>>>(A_h1, exitI, wo, bo, out);
}

// Round 6
// 22590.379 us; speedup vs baseline: 1.0011x; 1.0011x over previous
//
#include <hip/hip_runtime.h>

typedef unsigned int  u32;
typedef unsigned short u16;
typedef float v2f __attribute__((ext_vector_type(2)));

// B=8, NS=80, NN=81, H=256, L=2, STEPS=8, VOCAB=30000
#define ROWS 648          // B*NN

__device__ __forceinline__ float sigf(float x){ return 1.0f/(1.0f+__expf(-x)); }
__device__ __forceinline__ float tanh_fast(float x){
  float e = __expf(-2.0f*fabsf(x));
  float r = (1.0f-e)/(1.0f+e);
  return copysignf(r,x);
}
__device__ __forceinline__ u16 f2bf(float f){        // RTNE f32->bf16
  u32 u = __float_as_uint(f);
  u += 0x7FFFu + ((u>>16)&1u);
  return (u16)(u>>16);
}
__device__ __forceinline__ u32 packbf2(float lo, float hi){
  return (u32)f2bf(lo) | ((u32)f2bf(hi)<<16);
}
__device__ __forceinline__ float bf2f(u16 v){ return __uint_as_float(((u32)v)<<16); }
__device__ __forceinline__ float bflo(u32 u){ return __uint_as_float(u<<16); }
__device__ __forceinline__ float bfhi(u32 u){ return __uint_as_float(u & 0xFFFF0000u); }
__device__ __forceinline__ v2f unpk(u32 w){
  v2f r; r.x = bflo(w); r.y = bfhi(w); return r;
}

// ---------------- weight packing ----------------------------------------
// gate-quad, k-pair layout: dst[k2*1024 + j*4 + g] = pack(src[2k2][g*256+j], src[2k2+1][g*256+j])
__global__ void pack_gates(const float* __restrict__ A, const float* __restrict__ Bm,
                           u32* __restrict__ dst, int Krows){
  int id = blockIdx.x*256 + threadIdx.x;
  int tot = (Krows>>1)*1024;
  if (id >= tot) return;
  int k2 = id >> 10;
  int c  = id & 1023;
  int j = c >> 2, g = c & 3;
  int k0 = 2*k2, k1 = 2*k2+1;
  float v0 = (k0<256) ? A[k0*1024 + g*256 + j] : Bm[(k0-256)*1024 + g*256 + j];
  float v1 = (k1<256) ? A[k1*1024 + g*256 + j] : Bm[(k1-256)*1024 + g*256 + j];
  dst[id] = packbf2(v0, v1);
}

__global__ void pack_pairs(const float* __restrict__ src, u32* __restrict__ dst,
                           int Kpairs, int ncol){
  int id = blockIdx.x*256 + threadIdx.x;
  if (id >= Kpairs*ncol) return;
  int k2 = id / ncol, j = id - k2*ncol;
  dst[id] = packbf2(src[(2*k2)*ncol + j], src[(2*k2+1)*ncol + j]);
}

__global__ void k_init_p(float* __restrict__ p0){
  int i = blockIdx.x*256 + threadIdx.x;
  if (i < ROWS) p0[i] = ((i % 81)==0) ? 1.0f : 0.0f;
}

// ---------------- K1: statement embedder + X0 precompute ----------------
__global__ __launch_bounds__(512) void k_stmt_x0(
    const float* __restrict__ ne, const float* __restrict__ stWx, const float* __restrict__ stb,
    const float* __restrict__ skWx, const float* __restrict__ skb, float4* __restrict__ X0){
  __shared__ float xv[2][256];
  __shared__ float hv[2][256];
  int r = threadIdx.x >> 8, j = threadIdx.x & 255;
  int bn = blockIdx.x*2 + r;                    // 0..639
  xv[r][j] = ne[bn*256 + j];
  __syncthreads();
  float a0=stb[j], a2=stb[512+j], a3=stb[768+j];
  for (int k=0;k<256;k++){
    float x = xv[r][k];
    const float* w = stWx + k*1024;
    a0 = fmaf(x, w[j], a0); a2 = fmaf(x, w[512+j], a2); a3 = fmaf(x, w[768+j], a3);
  }
  float c = sigf(a0)*tanh_fast(a2);
  float h = sigf(a3)*tanh_fast(c);
  hv[r][j] = h;
  __syncthreads();
  a0=stb[1024+j]; a2=stb[1536+j]; a3=stb[1792+j];
  const float* W1 = stWx + 256*1024;
  for (int k=0;k<256;k++){
    float x = hv[r][k];
    const float* w = W1 + k*1024;
    a0 = fmaf(x, w[j], a0); a2 = fmaf(x, w[512+j], a2); a3 = fmaf(x, w[768+j], a3);
  }
  c = sigf(a0)*tanh_fast(a2);
  h = sigf(a3)*tanh_fast(c);
  __syncthreads();
  xv[r][j] = h;           // stmt row
  __syncthreads();
  float b0=skb[j], b1g=skb[256+j], b2=skb[512+j], b3=skb[768+j];
  for (int k=0;k<256;k++){
    float x = xv[r][k];
    const float* w = skWx + k*1024;
    b0 = fmaf(x, w[j], b0);     b1g = fmaf(x, w[256+j], b1g);
    b2 = fmaf(x, w[512+j], b2); b3 = fmaf(x, w[768+j], b3);
  }
  X0[bn*256 + j] = make_float4(b0,b1g,b2,b3);
}

// ---------------- K3: skip-encoder chains (v4: register-resident W) ------
// One block per chain (s,b); 1024 threads = 4 kh x 256 j; ONE block per CU.
// __launch_bounds__(1024,1): VGPR cap 512. Thread holds 96 uint4 = 384
// weight regs + ~50 working < 450 no-spill bound [m08]. Per-step consts
// (layer1 bias, LN scale/bias) live in LDS, not regs.
__global__ __launch_bounds__(1024, 1) void k_skip_chains(
    const float4* __restrict__ X0,
    const uint4* __restrict__ W0, const uint4* __restrict__ W1,
    const float* __restrict__ skb, const float* __restrict__ lnS, const float* __restrict__ lnB,
    float* __restrict__ skip){
  int chain = blockIdx.x;           // 0..639; s ascending => longest first
  int s = chain >> 3;
  int b = chain & 7;
  int tid = threadIdx.x;
  int kh = tid >> 8, j = tid & 255;
  // ---- preload weight slices into registers ----
  uint4 w0r[32];
  #pragma unroll
  for (int i=0;i<32;i++) w0r[i] = W0[(kh*32+i)*256 + j];
  uint4 w1r[64];
  #pragma unroll
  for (int i=0;i<64;i++) w1r[i] = W1[(kh*64+i)*256 + j];
  __shared__ float part[16*256];     // [(kh*4+g)][j] gate partials, 16KB
  __shared__ float h0buf[256];       // LN'd h0 (layer0 recurrent input)
  __shared__ float in1buf[512];      // [h0_raw | h1_ln] (layer1 input)
  __shared__ float cst[3072];        // [s1b(1024) | lnS(1024) | lnB(1024)]
  __shared__ float red[8];
  for (int i=tid; i<256; i+=1024) h0buf[i]=0.f;
  for (int i=tid; i<512; i+=1024) in1buf[i]=0.f;
  if (tid < 1024){
    cst[tid]        = skb[1024+tid];
    cst[1024+tid]   = lnS[tid];
    cst[2048+tid]   = lnB[tid];
  }
  float c0=0.f, c1=0.f;
  __syncthreads();
  for (int idx=s; idx<80; idx++){
    float4 gx;
    if (tid < 256) gx = X0[(b*80+idx)*256 + j];   // issue early, used after barrier
    // ---- layer0 matvec: h0 @ Wh0 (k2 slice kh*32..+32), weights from regs
    {
      v2f a0={0,0}, a1={0,0}, a2={0,0}, a3={0,0};
      #pragma unroll
      for (int i=0;i<32;i++){
        v2f hp = *(const v2f*)&h0buf[(kh*32+i)*2];
        uint4 w = w0r[i];
        a0 += hp*unpk(w.x); a1 += hp*unpk(w.y);
        a2 += hp*unpk(w.z); a3 += hp*unpk(w.w);
      }
      part[(kh*4+0)*256+j] = a0.x+a0.y;
      part[(kh*4+1)*256+j] = a1.x+a1.y;
      part[(kh*4+2)*256+j] = a2.x+a2.y;
      part[(kh*4+3)*256+j] = a3.x+a3.y;
    }
    __syncthreads();
    // ---- layer0 cell (threads j)
    if (tid < 256){
      float a0=gx.x, a1=gx.y, a2=gx.z, a3=gx.w;   // X0 includes sk_b0
      #pragma unroll
      for (int k=0;k<4;k++){
        a0 += part[(k*4+0)*256+j];
        a1 += part[(k*4+1)*256+j];
        a2 += part[(k*4+2)*256+j];
        a3 += part[(k*4+3)*256+j];
      }
      float ii=sigf(a0), ff=sigf(a1), gg=tanh_fast(a2), oo=sigf(a3);
      c0 = ff*c0 + ii*gg;
      float h0n = oo*tanh_fast(c0);
      in1buf[j] = h0n;
    }
    __syncthreads();
    // ---- layer1 matvec: [h0_raw|h1_ln] @ [Wx1;Wh1] (k2 slice kh*64..+64)
    {
      v2f a0={0,0}, a1={0,0}, a2={0,0}, a3={0,0};
      #pragma unroll
      for (int i=0;i<64;i++){
        v2f hp = *(const v2f*)&in1buf[(kh*64+i)*2];
        uint4 w = w1r[i];
        a0 += hp*unpk(w.x); a1 += hp*unpk(w.y);
        a2 += hp*unpk(w.z); a3 += hp*unpk(w.w);
      }
      part[(kh*4+0)*256+j] = a0.x+a0.y;
      part[(kh*4+1)*256+j] = a1.x+a1.y;
      part[(kh*4+2)*256+j] = a2.x+a2.y;
      part[(kh*4+3)*256+j] = a3.x+a3.y;
    }
    __syncthreads();
    // ---- layer1 cell + skip store + LN stats (threads j)
    float h0n_c=0.f, h1n_c=0.f;
    if (tid < 256){
      float a0=cst[j], a1=cst[256+j], a2=cst[512+j], a3=cst[768+j];
      #pragma unroll
      for (int k=0;k<4;k++){
        a0 += part[(k*4+0)*256+j];
        a1 += part[(k*4+1)*256+j];
        a2 += part[(k*4+2)*256+j];
        a3 += part[(k*4+3)*256+j];
      }
      float ii=sigf(a0), ff=sigf(a1), gg=tanh_fast(a2), oo=sigf(a3);
      c1 = ff*c1 + ii*gg;
      float h1n = oo*tanh_fast(c1);
      skip[((b*81 + s)*81 + (idx+1))*256 + j] = h1n;   // pre-LN output
      h0n_c = in1buf[j]; h1n_c = h1n;
      float sm = c0 + h0n_c + c1 + h1n_c;
      float sq = c0*c0 + h0n_c*h0n_c + c1*c1 + h1n_c*h1n_c;
      #pragma unroll
      for (int off=32; off; off>>=1){ sm += __shfl_xor(sm, off); sq += __shfl_xor(sq, off); }
      if ((j & 63) == 0){ red[j>>6] = sm; red[4+(j>>6)] = sq; }
    }
    __syncthreads();
    // ---- LN apply + publish next-step inputs (threads j)
    if (tid < 256){
      float sm = red[0]+red[1]+red[2]+red[3];
      float sq = red[4]+red[5]+red[6]+red[7];
      float mu = sm * (1.0f/1024.0f);
      float var = sq * (1.0f/1024.0f) - mu*mu;
      float rstd = rsqrtf(var + 1e-6f);
      c0 = (c0 - mu)*rstd*cst[1024+j] + cst[2048+j];
      float h0ln = (h0n_c - mu)*rstd*cst[1280+j] + cst[2304+j];
      c1 = (c1 - mu)*rstd*cst[1536+j] + cst[2560+j];
      float h1ln = (h1n_c - mu)*rstd*cst[1792+j] + cst[2816+j];
      h0buf[j] = h0ln;
      in1buf[256+j] = h1ln;
    }
    __syncthreads();
  }
}

// ---------------- K4: keys = skip @ ws + bs  (bf16 out) ------------------
__global__ __launch_bounds__(256) void k_keys(const float* __restrict__ skip,
    const u32* __restrict__ wspk, const float* __restrict__ bs, u16* __restrict__ keys){
  __shared__ float skr[8][256];
  int tid = threadIdx.x;
  int bn = blockIdx.x;
  float bsv = bs[tid];
  const float4* sk4 = (const float4*)skip;
  for (int m0=0; m0<81; m0+=8){
    int mc = (81-m0 < 8) ? (81-m0) : 8;
    for (int i=tid; i<mc*64; i+=256){
      int mm = i>>6, kk = i&63;
      float4 v = sk4[(bn*81 + m0 + mm)*64 + kk];
      skr[mm][4*kk+0]=v.x; skr[mm][4*kk+1]=v.y; skr[mm][4*kk+2]=v.z; skr[mm][4*kk+3]=v.w;
    }
    __syncthreads();
    v2f acc[8];
    #pragma unroll
    for (int qq=0;qq<8;qq++) acc[qq]=(v2f){0.f,0.f};
    for (int k2=0;k2<128;k2++){
      v2f w2 = unpk(wspk[k2*256+tid]);
      #pragma unroll
      for (int qq=0;qq<8;qq++){
        v2f sv = *(const v2f*)&skr[qq][2*k2];
        acc[qq] += sv*w2;
      }
    }
    for (int qq=0;qq<mc;qq++) keys[(bn*81+m0+qq)*256+tid] = f2bf(acc[qq].x+acc[qq].y+bsv);
    __syncthreads();
  }
}

// ---------------- Kb: fused q + logits -> softmax -> t -------------------
// mode 0: only m==1; mode 1: m>n || m==80; mode 2: only m==80
__global__ __launch_bounds__(256) void k_attn(
    const float* __restrict__ c0g, const float* __restrict__ h0g,
    const float* __restrict__ c1g, const float* __restrict__ h1g,
    const u32* __restrict__ wkp, const float* __restrict__ bk,
    const u16* __restrict__ keys, const float* __restrict__ w1,
    const float* __restrict__ pcur, float* __restrict__ t, int mode){
  int bn = blockIdx.x; int n = bn % 81;
  int tid = threadIdx.x;
  float pv = pcur[bn];
  if (pv == 0.0f){
    if (tid < 81) t[bn*81 + tid] = 0.0f;
    return;
  }
  __shared__ float hc[1024];
  __shared__ float qv[256];
  __shared__ float lg[81];
  hc[tid]      = c0g[bn*256+tid];
  hc[256+tid]  = h0g[bn*256+tid];
  hc[512+tid]  = c1g[bn*256+tid];
  hc[768+tid]  = h1g[bn*256+tid];
  if (tid < 81) lg[tid] = -3e38f;
  __syncthreads();
  v2f A = {bk[tid], 0.f};
  #pragma unroll 8
  for (int k2=0;k2<512;k2++){
    v2f hp = *(const v2f*)&hc[2*k2];
    A += hp*unpk(wkp[k2*256+tid]);
  }
  qv[tid] = A.x + A.y;
  __syncthreads();
  int lane = tid & 63, wv = tid >> 6;
  float w1v0 = w1[lane], w1v1 = w1[64+lane], w1v2 = w1[128+lane], w1v3 = w1[192+lane];
  for (int m = wv; m < 81; m += 4){
    bool um = (mode==0) ? (m==1) : (mode==2) ? (m==80) : (m>n || m==80);
    if (!um) continue;
    const u16* kr = keys + (bn*81+m)*256;
    float acc;
    acc  = tanh_fast(qv[lane]     + bf2f(kr[lane]))     * w1v0;
    acc += tanh_fast(qv[64+lane]  + bf2f(kr[64+lane]))  * w1v1;
    acc += tanh_fast(qv[128+lane] + bf2f(kr[128+lane])) * w1v2;
    acc += tanh_fast(qv[192+lane] + bf2f(kr[192+lane])) * w1v3;
    #pragma unroll
    for (int off=32; off; off>>=1) acc += __shfl_xor(acc, off);
    if (lane==0) lg[m] = acc;      // b1 omitted: softmax-invariant
  }
  __syncthreads();
  if (tid < 64){
    float v1 = lg[tid];
    float v2 = (tid<17) ? lg[64+tid] : -3e38f;
    float mx = fmaxf(v1, v2);
    #pragma unroll
    for (int off=32; off; off>>=1) mx = fmaxf(mx, __shfl_xor(mx, off));
    float e1 = __expf(v1-mx);
    float e2 = (tid<17) ? __expf(v2-mx) : 0.0f;
    float ssum = e1+e2;
    #pragma unroll
    for (int off=32; off; off>>=1) ssum += __shfl_xor(ssum, off);
    float sc = pv / ssum;
    t[bn*81 + tid] = e1*sc;
    if (tid<17) t[bn*81 + 64+tid] = e2*sc;
  }
}

// ---------------- Kc: x_in/prop einsums + ex-LSTM step + new_p -----------
__global__ __launch_bounds__(1024) void k_update(
    const float* __restrict__ t, const float* __restrict__ skip,
    const float* __restrict__ c0i, const float* __restrict__ h0i,
    const float* __restrict__ c1i, const float* __restrict__ h1i,
    const uint4* __restrict__ WA, const uint4* __restrict__ WB,
    const float* __restrict__ exb,
    float* __restrict__ c0o, float* __restrict__ h0o,
    float* __restrict__ c1o, float* __restrict__ h1o,
    float* __restrict__ pnext){
  int rr = threadIdx.x >> 8, j = threadIdx.x & 255;
  int row = blockIdx.x*4 + rr;
  int b = row / 81, m = row - b*81;
  __shared__ float tcol[4][81];
  __shared__ float xh[4][512];
  if (j < 81) tcol[rr][j] = t[(b*81 + j)*81 + m];
  __syncthreads();
  float xa=0.f, c0p=0.f, h0p=0.f, c1p=0.f, h1p=0.f, ts=0.f;
  for (int n=0;n<81;n++){
    float tv = tcol[rr][n];
    ts += tv;
    if (tv != 0.0f){
      xa  = fmaf(tv, skip[((b*81+n)*81 + m)*256 + j], xa);
      int st = (b*81+n)*256 + j;
      c0p = fmaf(tv, c0i[st], c0p);
      h0p = fmaf(tv, h0i[st], h0p);
      c1p = fmaf(tv, c1i[st], c1p);
      h1p = fmaf(tv, h1i[st], h1p);
    }
  }
  bool alive = (ts != 0.0f);
  float inv = 1.0f/(ts + 1e-7f);
  xa*=inv; c0p*=inv; h0p*=inv; c1p*=inv; h1p*=inv;
  if (j==0) pnext[row] = ts;
  xh[rr][j] = xa; xh[rr][256+j] = h0p;
  __syncthreads();
  float c0n=0.f, h0n=0.f;
  if (alive){
    v2f A0={exb[j],0.f}, A1={exb[256+j],0.f}, A2={exb[512+j],0.f}, A3={exb[768+j],0.f};
    #pragma unroll 8
    for (int k2=0;k2<256;k2++){
      v2f hp = *(const v2f*)&xh[rr][2*k2];
      uint4 w = WA[k2*256+j];
      A0 += hp*unpk(w.x); A1 += hp*unpk(w.y);
      A2 += hp*unpk(w.z); A3 += hp*unpk(w.w);
    }
    float a0=A0.x+A0.y, a1=A1.x+A1.y, a2=A2.x+A2.y, a3=A3.x+A3.y;
    c0n = sigf(a1)*c0p + sigf(a0)*tanh_fast(a2);
    h0n = sigf(a3)*tanh_fast(c0n);
  }
  __syncthreads();
  xh[rr][j] = h0n; xh[rr][256+j] = h1p;
  __syncthreads();
  if (alive){
    v2f A0={exb[1024+j],0.f}, A1={exb[1280+j],0.f}, A2={exb[1536+j],0.f}, A3={exb[1792+j],0.f};
    #pragma unroll 8
    for (int k2=0;k2<256;k2++){
      v2f hp = *(const v2f*)&xh[rr][2*k2];
      uint4 w = WB[k2*256+j];
      A0 += hp*unpk(w.x); A1 += hp*unpk(w.y);
      A2 += hp*unpk(w.z); A3 += hp*unpk(w.w);
    }
    float a0=A0.x+A0.y, a1=A1.x+A1.y, a2=A2.x+A2.y, a3=A3.x+A3.y;
    float c1n = sigf(a1)*c1p + sigf(a0)*tanh_fast(a2);
    float h1n = sigf(a3)*tanh_fast(c1n);
    int o = row*256 + j;
    c0o[o]=c0n; h0o[o]=h0n; c1o[o]=c1n; h1o[o]=h1n;
  }
}

// ---------------- K6: out = h_exit @ wo + bo -----------------------------
__global__ __launch_bounds__(256) void k_out(
    const float* __restrict__ h1f, const int* __restrict__ exitIdx,
    const float* __restrict__ wo, const float* __restrict__ bo, float* __restrict__ out){
  __shared__ float hv[8][256];
  int tid = threadIdx.x;
  for (int i = tid; i < 2048; i += 256){
    int b = i >> 8, k = i & 255;
    hv[b][k] = h1f[(b*81 + exitIdx[b])*256 + k];
  }
  __syncthreads();
  int v = blockIdx.x*256 + tid;
  if (v >= 30000) return;
  float acc[8];
  #pragma unroll
  for (int b=0;b<8;b++) acc[b] = bo[v];
  for (int k=0;k<256;k++){
    float w = wo[k*30000 + v];
    #pragma unroll
    for (int b=0;b<8;b++) acc[b] = fmaf(hv[b][k], w, acc[b]);
  }
  #pragma unroll
  for (int b=0;b<8;b++) out[b*30000+v] = acc[b];
}

// ---------------- launch --------------------------------------------------
extern "C" void kernel_launch(void* const* d_in, const int* in_sizes, int n_in,
                              void* d_out, int out_size, void* d_ws, size_t ws_size,
                              hipStream_t stream){
  (void)in_sizes; (void)n_in; (void)out_size;
  const float* ne    = (const float*)d_in[0];
  const int*   exitI = (const int*)d_in[10];
  const float* stWx  = (const float*)d_in[12];
  const float* stb   = (const float*)d_in[14];
  const float* skWx  = (const float*)d_in[15];
  const float* skWh  = (const float*)d_in[16];
  const float* skb   = (const float*)d_in[17];
  const float* lnS   = (const float*)d_in[18];
  const float* lnB   = (const float*)d_in[19];
  const float* exWx  = (const float*)d_in[20];
  const float* exWh  = (const float*)d_in[21];
  const float* exb   = (const float*)d_in[22];
  const float* wk    = (const float*)d_in[23];
  const float* bk    = (const float*)d_in[24];
  const float* wsm   = (const float*)d_in[25];
  const float* bs    = (const float*)d_in[26];
  const float* w1    = (const float*)d_in[27];
  const float* wo    = (const float*)d_in[29];
  const float* bo    = (const float*)d_in[30];
  float* out = (float*)d_out;

  char* w = (char*)d_ws;
  size_t off = 0;
  auto alloc = [&](size_t bytes)->char*{
    char* p = w + off; off += (bytes + 255) & ~size_t(255); return p;
  };
  float4* X0   = (float4*)alloc((size_t)640*256*16);
  u32* W0pk    = (u32*)alloc((size_t)128*1024*4);
  u32* W1pk    = (u32*)alloc((size_t)256*1024*4);
  u32* WApk    = (u32*)alloc((size_t)256*1024*4);
  u32* WBpk    = (u32*)alloc((size_t)256*1024*4);
  u32* wkp     = (u32*)alloc((size_t)512*256*4);
  u32* wspk    = (u32*)alloc((size_t)128*256*4);
  float* skip  = (float*)alloc((size_t)8*81*81*256*4);   // fp32
  u16* keys    = (u16*)alloc((size_t)8*81*81*256*2);     // bf16
  float* tb    = (float*)alloc((size_t)ROWS*81*4);
  float* p0    = (float*)alloc(ROWS*4);
  float* p1    = (float*)alloc(ROWS*4);
  float* stA   = (float*)alloc((size_t)4*ROWS*256*4);
  float* stB   = (float*)alloc((size_t)4*ROWS*256*4);
  if (off > ws_size) return;   // workspace too small — surfaces as absmax fail

  const size_t ST = (size_t)ROWS*256;
  float *A_c0=stA, *A_h0=stA+ST, *A_c1=stA+2*ST, *A_h1=stA+3*ST;
  float *B_c0=stB, *B_h0=stB+ST, *B_c1=stB+2*ST, *B_h1=stB+3*ST;

  hipMemsetAsync(skip, 0, (size_t)8*81*81*256*4, stream);
  hipMemsetAsync(stA, 0, (size_t)4*ROWS*256*4, stream);
  hipMemsetAsync(stB, 0, (size_t)4*ROWS*256*4, stream);
  k_init_p<<<3,256,0,stream>>>(p0);

  pack_gates<<<512, 256, 0, stream>>>(skWh, skWh, W0pk, 256);                       // Wh0
  pack_gates<<<1024,256, 0, stream>>>(skWx+256*1024, skWh+256*1024, W1pk, 512);     // [Wx1;Wh1]
  pack_gates<<<1024,256, 0, stream>>>(exWx, exWh, WApk, 512);                       // [exWx0;exWh0]
  pack_gates<<<1024,256, 0, stream>>>(exWx+256*1024, exWh+256*1024, WBpk, 512);     // [exWx1;exWh1]
  pack_pairs<<<512, 256, 0, stream>>>(wk, wkp, 512, 256);
  pack_pairs<<<128, 256, 0, stream>>>(wsm, wspk, 128, 256);

  k_stmt_x0<<<320, 512, 0, stream>>>(ne, stWx, stb, skWx, skb, X0);
  k_skip_chains<<<640, 1024, 0, stream>>>(X0, (const uint4*)W0pk, (const uint4*)W1pk,
                                          skb, lnS, lnB, skip);
  k_keys<<<648, 256, 0, stream>>>(skip, wspk, bs, keys);

  float* pc = p0; float* pn = p1;
  for (int s=0; s<8; s++){
    float *ic0,*ih0,*ic1,*ih1,*oc0,*oh0,*oc1,*oh1;
    if ((s & 1) == 0){ ic0=A_c0; ih0=A_h0; ic1=A_c1; ih1=A_h1; oc0=B_c0; oh0=B_h0; oc1=B_c1; oh1=B_h1; }
    else             { ic0=B_c0; ih0=B_h0; ic1=B_c1; ih1=B_h1; oc0=A_c0; oh0=A_h0; oc1=A_c1; oh1=A_h1; }
    int mode = (s==0) ? 0 : ((s==7) ? 2 : 1);
    k_attn<<<648, 256, 0, stream>>>(ic0, ih0, ic1, ih1, wkp, bk, keys, w1, pc, tb, mode);
    k_update<<<162, 1024, 0, stream>>>(tb, skip, ic0, ih0, ic1, ih1,
                                       (const uint4*)WApk, (const uint4*)WBpk, exb,
                                       oc0, oh0, oc1, oh1, pn);
    float* tmp = pc; pc = pn; pn = tmp;
  }
  // final states are in buffer A (step 7 writes A)
  k_out<<<(30000+255)/256, 256, 0, stream>>>(A_h1, exitI, wo, bo, out);
}

// Round 7
// 4369.434 us; speedup vs baseline: 5.1758x; 5.1701x over previous
//
#include <hip/hip_runtime.h>

typedef unsigned int  u32;
typedef unsigned short u16;
typedef float v2f __attribute__((ext_vector_type(2)));

// B=8, NS=80, NN=81, H=256, L=2, STEPS=8, VOCAB=30000
#define ROWS 648          // B*NN

__device__ __forceinline__ float sigf(float x){ return 1.0f/(1.0f+__expf(-x)); }
__device__ __forceinline__ float tanh_fast(float x){
  float e = __expf(-2.0f*fabsf(x));
  float r = (1.0f-e)/(1.0f+e);
  return copysignf(r,x);
}
__device__ __forceinline__ u16 f2bf(float f){        // RTNE f32->bf16
  u32 u = __float_as_uint(f);
  u += 0x7FFFu + ((u>>16)&1u);
  return (u16)(u>>16);
}
__device__ __forceinline__ u32 packbf2(float lo, float hi){
  return (u32)f2bf(lo) | ((u32)f2bf(hi)<<16);
}
__device__ __forceinline__ float bf2f(u16 v){ return __uint_as_float(((u32)v)<<16); }
__device__ __forceinline__ float bflo(u32 u){ return __uint_as_float(u<<16); }
__device__ __forceinline__ float bfhi(u32 u){ return __uint_as_float(u & 0xFFFF0000u); }
__device__ __forceinline__ v2f unpk(u32 w){
  v2f r; r.x = bflo(w); r.y = bfhi(w); return r;
}

// ---------------- weight packing ----------------------------------------
// gate-quad, k-pair layout: dst[k2*1024 + j*4 + g] = pack(src[2k2][g*256+j], src[2k2+1][g*256+j])
__global__ void pack_gates(const float* __restrict__ A, const float* __restrict__ Bm,
                           u32* __restrict__ dst, int Krows){
  int id = blockIdx.x*256 + threadIdx.x;
  int tot = (Krows>>1)*1024;
  if (id >= tot) return;
  int k2 = id >> 10;
  int c  = id & 1023;
  int j = c >> 2, g = c & 3;
  int k0 = 2*k2, k1 = 2*k2+1;
  float v0 = (k0<256) ? A[k0*1024 + g*256 + j] : Bm[(k0-256)*1024 + g*256 + j];
  float v1 = (k1<256) ? A[k1*1024 + g*256 + j] : Bm[(k1-256)*1024 + g*256 + j];
  dst[id] = packbf2(v0, v1);
}

// scaled variant: rows k<256 from A (scaled by scA), k>=256 from Bm (scaled by scB); null => 1.0
__global__ void pack_gates_sc(const float* __restrict__ A, const float* __restrict__ Bm,
                              const float* __restrict__ scA, const float* __restrict__ scB,
                              u32* __restrict__ dst, int Krows){
  int id = blockIdx.x*256 + threadIdx.x;
  int tot = (Krows>>1)*1024;
  if (id >= tot) return;
  int k2 = id >> 10;
  int c  = id & 1023;
  int j = c >> 2, g = c & 3;
  int k0 = 2*k2, k1 = 2*k2+1;
  float v0, v1;
  if (k0 < 256){ v0 = A[k0*1024 + g*256 + j];        if (scA) v0 *= scA[k0]; }
  else         { v0 = Bm[(k0-256)*1024 + g*256 + j]; if (scB) v0 *= scB[k0-256]; }
  if (k1 < 256){ v1 = A[k1*1024 + g*256 + j];        if (scA) v1 *= scA[k1]; }
  else         { v1 = Bm[(k1-256)*1024 + g*256 + j]; if (scB) v1 *= scB[k1-256]; }
  dst[id] = packbf2(v0, v1);
}

__global__ void pack_pairs(const float* __restrict__ src, u32* __restrict__ dst,
                           int Kpairs, int ncol){
  int id = blockIdx.x*256 + threadIdx.x;
  if (id >= Kpairs*ncol) return;
  int k2 = id / ncol, j = id - k2*ncol;
  dst[id] = packbf2(src[(2*k2)*ncol + j], src[(2*k2+1)*ncol + j]);
}

__global__ void k_init_p(float* __restrict__ p0){
  int i = blockIdx.x*256 + threadIdx.x;
  if (i < ROWS) p0[i] = ((i % 81)==0) ? 1.0f : 0.0f;
}

// LN-fold constants: uv[id=jh*4+g]: u0 | v0(+1024) | u1(+2048) | v1(+3072) | cb1(+4096)
__global__ void k_uv(const float* __restrict__ Wh0, const float* __restrict__ Wh1,
                     const float* __restrict__ lnS, const float* __restrict__ lnB,
                     const float* __restrict__ skb, float* __restrict__ uv){
  int id = blockIdx.x*256 + threadIdx.x;       // 0..1023
  int g = id & 3, jh = id >> 2;
  float u0=0,v0=0,u1=0,v1=0;
  for (int k=0;k<256;k++){
    float w0 = Wh0[k*1024 + g*256 + jh];
    u0 = fmaf(lnS[256+k], w0, u0); v0 = fmaf(lnB[256+k], w0, v0);
    float w1 = Wh1[k*1024 + g*256 + jh];
    u1 = fmaf(lnS[768+k], w1, u1); v1 = fmaf(lnB[768+k], w1, v1);
  }
  uv[id]=u0; uv[1024+id]=v0; uv[2048+id]=u1; uv[3072+id]=v1;
  uv[4096+id]=skb[1024 + g*256 + jh];
}

// ---------------- K1: statement embedder + X0 precompute ----------------
__global__ __launch_bounds__(512) void k_stmt_x0(
    const float* __restrict__ ne, const float* __restrict__ stWx, const float* __restrict__ stb,
    const float* __restrict__ skWx, const float* __restrict__ skb, float4* __restrict__ X0){
  __shared__ float xv[2][256];
  __shared__ float hv[2][256];
  int r = threadIdx.x >> 8, j = threadIdx.x & 255;
  int bn = blockIdx.x*2 + r;                    // 0..639
  xv[r][j] = ne[bn*256 + j];
  __syncthreads();
  float a0=stb[j], a2=stb[512+j], a3=stb[768+j];
  for (int k=0;k<256;k++){
    float x = xv[r][k];
    const float* w = stWx + k*1024;
    a0 = fmaf(x, w[j], a0); a2 = fmaf(x, w[512+j], a2); a3 = fmaf(x, w[768+j], a3);
  }
  float c = sigf(a0)*tanh_fast(a2);
  float h = sigf(a3)*tanh_fast(c);
  hv[r][j] = h;
  __syncthreads();
  a0=stb[1024+j]; a2=stb[1536+j]; a3=stb[1792+j];
  const float* W1 = stWx + 256*1024;
  for (int k=0;k<256;k++){
    float x = hv[r][k];
    const float* w = W1 + k*1024;
    a0 = fmaf(x, w[j], a0); a2 = fmaf(x, w[512+j], a2); a3 = fmaf(x, w[768+j], a3);
  }
  c = sigf(a0)*tanh_fast(a2);
  h = sigf(a3)*tanh_fast(c);
  __syncthreads();
  xv[r][j] = h;           // stmt row
  __syncthreads();
  float b0=skb[j], b1g=skb[256+j], b2=skb[512+j], b3=skb[768+j];
  for (int k=0;k<256;k++){
    float x = xv[r][k];
    const float* w = skWx + k*1024;
    b0 = fmaf(x, w[j], b0);     b1g = fmaf(x, w[256+j], b1g);
    b2 = fmaf(x, w[512+j], b2); b3 = fmaf(x, w[768+j], b3);
  }
  X0[bn*256 + j] = make_float4(b0,b1g,b2,b3);
}

// ---------------- wavefront skip-encoder ---------------------------------
// Global step idx: all chains s<=idx do their LSTM step simultaneously.
// Row r = s*8+b (640 rows). LN folded into matvecs via (mu,rstd) scalars:
//   h_ln @ W = rstd*(h_raw @ diag(lnS_seg)W) - rstd*mu*u + v.
// Phase A (k_wf0): layer0 matvec+cell. Phase B (k_wf1): layer1+skip+stats.
// grid (idx+1, 8): block = (s-group g, j-slice p); 256 thr = 8 rows x 32 jh.
__global__ __launch_bounds__(256) void k_wf0(
    const float4* __restrict__ X0, const uint4* __restrict__ W0p,
    const float4* __restrict__ uv,
    const float* __restrict__ H0in, float* __restrict__ H0out,
    float* __restrict__ C0, const float* __restrict__ stats,
    const float* __restrict__ lnS, const float* __restrict__ lnB, int idx){
  int g = blockIdx.x, p = blockIdx.y;
  int tid = threadIdx.x, rl = tid>>5, jl = tid&31;
  int jh = p*32 + jl;
  int r = g*8 + rl;
  bool start = (g == idx);                 // block-uniform
  __shared__ float hs[8][256];
  float mu=0.f, rstd=0.f;
  if (!start){
    for (int i=tid;i<2048;i+=256) hs[i>>8][i&255] = H0in[(g*8+(i>>8))*256 + (i&255)];
    float sm = stats[((idx-1)*640 + r)*2+0];
    float sq = stats[((idx-1)*640 + r)*2+1];
    mu = sm*(1.f/1024.f);
    float var = sq*(1.f/1024.f) - mu*mu;
    rstd = rsqrtf(var + 1e-6f);
  }
  __syncthreads();
  float4 x0 = X0[(rl*80 + idx)*256 + jh];  // b = rl
  float a0,a1,a2,a3;
  if (start){ a0=x0.x; a1=x0.y; a2=x0.z; a3=x0.w; }
  else{
    v2f A0={0,0},A1={0,0},A2={0,0},A3={0,0};
    #pragma unroll 8
    for (int k2=0;k2<128;k2++){
      uint4 w = W0p[k2*256 + jh];
      v2f hp = *(const v2f*)&hs[rl][2*k2];
      A0 += hp*unpk(w.x); A1 += hp*unpk(w.y);
      A2 += hp*unpk(w.z); A3 += hp*unpk(w.w);
    }
    float4 u0 = uv[jh], v0 = uv[256+jh];
    float rm = rstd*mu;
    a0 = x0.x + rstd*(A0.x+A0.y) - rm*u0.x + v0.x;
    a1 = x0.y + rstd*(A1.x+A1.y) - rm*u0.y + v0.y;
    a2 = x0.z + rstd*(A2.x+A2.y) - rm*u0.z + v0.z;
    a3 = x0.w + rstd*(A3.x+A3.y) - rm*u0.w + v0.w;
  }
  int o = r*256 + jh;
  float c0ln = start ? 0.f : (C0[o]-mu)*rstd*lnS[jh] + lnB[jh];
  float ii=sigf(a0), ff=sigf(a1), gg=tanh_fast(a2), oo=sigf(a3);
  float c0n = ff*c0ln + ii*gg;
  float h0n = oo*tanh_fast(c0n);
  C0[o]=c0n; H0out[o]=h0n;
}

__global__ __launch_bounds__(256) void k_wf1(
    const uint4* __restrict__ W1p, const float4* __restrict__ uv,
    const float* __restrict__ H0new, const float* __restrict__ H1in,
    float* __restrict__ H1out, float* __restrict__ C1, const float* __restrict__ C0,
    float* __restrict__ skip, float* __restrict__ stats,
    const float* __restrict__ lnS, const float* __restrict__ lnB, int idx){
  int g = blockIdx.x, p = blockIdx.y;
  int tid = threadIdx.x, rl = tid>>5, jl = tid&31;
  int jh = p*32 + jl;
  int r = g*8 + rl;
  bool start = (g == idx);
  __shared__ float h0s[8][256];
  __shared__ float h1s[8][256];
  for (int i=tid;i<2048;i+=256) h0s[i>>8][i&255] = H0new[(g*8+(i>>8))*256 + (i&255)];
  float mu=0.f, rstd=0.f;
  if (!start){
    for (int i=tid;i<2048;i+=256) h1s[i>>8][i&255] = H1in[(g*8+(i>>8))*256 + (i&255)];
    float sm = stats[((idx-1)*640 + r)*2+0];
    float sq = stats[((idx-1)*640 + r)*2+1];
    mu = sm*(1.f/1024.f);
    float var = sq*(1.f/1024.f) - mu*mu;
    rstd = rsqrtf(var + 1e-6f);
  }
  __syncthreads();
  v2f A0={0,0},A1={0,0},A2={0,0},A3={0,0};
  #pragma unroll 8
  for (int k2=0;k2<128;k2++){
    uint4 w = W1p[k2*256 + jh];
    v2f hp = *(const v2f*)&h0s[rl][2*k2];
    A0 += hp*unpk(w.x); A1 += hp*unpk(w.y);
    A2 += hp*unpk(w.z); A3 += hp*unpk(w.w);
  }
  float4 cb = uv[1024+jh];
  float a0 = A0.x+A0.y + cb.x;
  float a1 = A1.x+A1.y + cb.y;
  float a2 = A2.x+A2.y + cb.z;
  float a3 = A3.x+A3.y + cb.w;
  if (!start){
    v2f B0={0,0},B1={0,0},B2={0,0},B3={0,0};
    #pragma unroll 8
    for (int k2=0;k2<128;k2++){
      uint4 w = W1p[(128+k2)*256 + jh];
      v2f hp = *(const v2f*)&h1s[rl][2*k2];
      B0 += hp*unpk(w.x); B1 += hp*unpk(w.y);
      B2 += hp*unpk(w.z); B3 += hp*unpk(w.w);
    }
    float4 u1 = uv[512+jh], v1 = uv[768+jh];
    float rm = rstd*mu;
    a0 += rstd*(B0.x+B0.y) - rm*u1.x + v1.x;
    a1 += rstd*(B1.x+B1.y) - rm*u1.y + v1.y;
    a2 += rstd*(B2.x+B2.y) - rm*u1.z + v1.z;
    a3 += rstd*(B3.x+B3.y) - rm*u1.w + v1.w;
  }
  int o = r*256 + jh;
  float c1ln = start ? 0.f : (C1[o]-mu)*rstd*lnS[512+jh] + lnB[512+jh];
  float ii=sigf(a0), ff=sigf(a1), gg=tanh_fast(a2), oo=sigf(a3);
  float c1n = ff*c1ln + ii*gg;
  float h1n = oo*tanh_fast(c1n);
  C1[o]=c1n; H1out[o]=h1n;
  skip[((rl*81 + g)*81 + (idx+1))*256 + jh] = h1n;   // b=rl, s=g, pre-LN
  float c0n = C0[o], h0n = h0s[rl][jh];
  float sm = c0n + h0n + c1n + h1n;
  float sq = c0n*c0n + h0n*h0n + c1n*c1n + h1n*h1n;
  #pragma unroll
  for (int off=16; off; off>>=1){ sm += __shfl_xor(sm, off); sq += __shfl_xor(sq, off); }
  if (jl == 0){
    atomicAdd(&stats[(idx*640 + r)*2+0], sm);
    atomicAdd(&stats[(idx*640 + r)*2+1], sq);
  }
}

// ---------------- K4: keys = skip @ ws + bs  (bf16 out) ------------------
__global__ __launch_bounds__(256) void k_keys(const float* __restrict__ skip,
    const u32* __restrict__ wspk, const float* __restrict__ bs, u16* __restrict__ keys){
  __shared__ float skr[8][256];
  int tid = threadIdx.x;
  int bn = blockIdx.x;
  float bsv = bs[tid];
  const float4* sk4 = (const float4*)skip;
  for (int m0=0; m0<81; m0+=8){
    int mc = (81-m0 < 8) ? (81-m0) : 8;
    for (int i=tid; i<mc*64; i+=256){
      int mm = i>>6, kk = i&63;
      float4 v = sk4[(bn*81 + m0 + mm)*64 + kk];
      skr[mm][4*kk+0]=v.x; skr[mm][4*kk+1]=v.y; skr[mm][4*kk+2]=v.z; skr[mm][4*kk+3]=v.w;
    }
    __syncthreads();
    v2f acc[8];
    #pragma unroll
    for (int qq=0;qq<8;qq++) acc[qq]=(v2f){0.f,0.f};
    for (int k2=0;k2<128;k2++){
      v2f w2 = unpk(wspk[k2*256+tid]);
      #pragma unroll
      for (int qq=0;qq<8;qq++){
        v2f sv = *(const v2f*)&skr[qq][2*k2];
        acc[qq] += sv*w2;
      }
    }
    for (int qq=0;qq<mc;qq++) keys[(bn*81+m0+qq)*256+tid] = f2bf(acc[qq].x+acc[qq].y+bsv);
    __syncthreads();
  }
}

// ---------------- Kb: fused q + logits -> softmax -> t -------------------
// mode 0: only m==1; mode 1: m>n || m==80; mode 2: only m==80
__global__ __launch_bounds__(256) void k_attn(
    const float* __restrict__ c0g, const float* __restrict__ h0g,
    const float* __restrict__ c1g, const float* __restrict__ h1g,
    const u32* __restrict__ wkp, const float* __restrict__ bk,
    const u16* __restrict__ keys, const float* __restrict__ w1,
    const float* __restrict__ pcur, float* __restrict__ t, int mode){
  int bn = blockIdx.x; int n = bn % 81;
  int tid = threadIdx.x;
  float pv = pcur[bn];
  if (pv == 0.0f){
    if (tid < 81) t[bn*81 + tid] = 0.0f;
    return;
  }
  __shared__ float hc[1024];
  __shared__ float qv[256];
  __shared__ float lg[81];
  hc[tid]      = c0g[bn*256+tid];
  hc[256+tid]  = h0g[bn*256+tid];
  hc[512+tid]  = c1g[bn*256+tid];
  hc[768+tid]  = h1g[bn*256+tid];
  if (tid < 81) lg[tid] = -3e38f;
  __syncthreads();
  v2f A = {bk[tid], 0.f};
  #pragma unroll 8
  for (int k2=0;k2<512;k2++){
    v2f hp = *(const v2f*)&hc[2*k2];
    A += hp*unpk(wkp[k2*256+tid]);
  }
  qv[tid] = A.x + A.y;
  __syncthreads();
  int lane = tid & 63, wv = tid >> 6;
  float w1v0 = w1[lane], w1v1 = w1[64+lane], w1v2 = w1[128+lane], w1v3 = w1[192+lane];
  for (int m = wv; m < 81; m += 4){
    bool um = (mode==0) ? (m==1) : (mode==2) ? (m==80) : (m>n || m==80);
    if (!um) continue;
    const u16* kr = keys + (bn*81+m)*256;
    float acc;
    acc  = tanh_fast(qv[lane]     + bf2f(kr[lane]))     * w1v0;
    acc += tanh_fast(qv[64+lane]  + bf2f(kr[64+lane]))  * w1v1;
    acc += tanh_fast(qv[128+lane] + bf2f(kr[128+lane])) * w1v2;
    acc += tanh_fast(qv[192+lane] + bf2f(kr[192+lane])) * w1v3;
    #pragma unroll
    for (int off=32; off; off>>=1) acc += __shfl_xor(acc, off);
    if (lane==0) lg[m] = acc;      // b1 omitted: softmax-invariant
  }
  __syncthreads();
  if (tid < 64){
    float v1 = lg[tid];
    float v2 = (tid<17) ? lg[64+tid] : -3e38f;
    float mx = fmaxf(v1, v2);
    #pragma unroll
    for (int off=32; off; off>>=1) mx = fmaxf(mx, __shfl_xor(mx, off));
    float e1 = __expf(v1-mx);
    float e2 = (tid<17) ? __expf(v2-mx) : 0.0f;
    float ssum = e1+e2;
    #pragma unroll
    for (int off=32; off; off>>=1) ssum += __shfl_xor(ssum, off);
    float sc = pv / ssum;
    t[bn*81 + tid] = e1*sc;
    if (tid<17) t[bn*81 + 64+tid] = e2*sc;
  }
}

// ---------------- Kc: x_in/prop einsums + ex-LSTM step + new_p -----------
__global__ __launch_bounds__(1024) void k_update(
    const float* __restrict__ t, const float* __restrict__ skip,
    const float* __restrict__ c0i, const float* __restrict__ h0i,
    const float* __restrict__ c1i, const float* __restrict__ h1i,
    const uint4* __restrict__ WA, const uint4* __restrict__ WB,
    const float* __restrict__ exb,
    float* __restrict__ c0o, float* __restrict__ h0o,
    float* __restrict__ c1o, float* __restrict__ h1o,
    float* __restrict__ pnext){
  int rr = threadIdx.x >> 8, j = threadIdx.x & 255;
  int row = blockIdx.x*4 + rr;
  int b = row / 81, m = row - b*81;
  __shared__ float tcol[4][81];
  __shared__ float xh[4][512];
  if (j < 81) tcol[rr][j] = t[(b*81 + j)*81 + m];
  __syncthreads();
  float xa=0.f, c0p=0.f, h0p=0.f, c1p=0.f, h1p=0.f, ts=0.f;
  for (int n=0;n<81;n++){
    float tv = tcol[rr][n];
    ts += tv;
    if (tv != 0.0f){
      xa  = fmaf(tv, skip[((b*81+n)*81 + m)*256 + j], xa);
      int st = (b*81+n)*256 + j;
      c0p = fmaf(tv, c0i[st], c0p);
      h0p = fmaf(tv, h0i[st], h0p);
      c1p = fmaf(tv, c1i[st], c1p);
      h1p = fmaf(tv, h1i[st], h1p);
    }
  }
  bool alive = (ts != 0.0f);
  float inv = 1.0f/(ts + 1e-7f);
  xa*=inv; c0p*=inv; h0p*=inv; c1p*=inv; h1p*=inv;
  if (j==0) pnext[row] = ts;
  xh[rr][j] = xa; xh[rr][256+j] = h0p;
  __syncthreads();
  float c0n=0.f, h0n=0.f;
  if (alive){
    v2f A0={exb[j],0.f}, A1={exb[256+j],0.f}, A2={exb[512+j],0.f}, A3={exb[768+j],0.f};
    #pragma unroll 8
    for (int k2=0;k2<256;k2++){
      v2f hp = *(const v2f*)&xh[rr][2*k2];
      uint4 w = WA[k2*256+j];
      A0 += hp*unpk(w.x); A1 += hp*unpk(w.y);
      A2 += hp*unpk(w.z); A3 += hp*unpk(w.w);
    }
    float a0=A0.x+A0.y, a1=A1.x+A1.y, a2=A2.x+A2.y, a3=A3.x+A3.y;
    c0n = sigf(a1)*c0p + sigf(a0)*tanh_fast(a2);
    h0n = sigf(a3)*tanh_fast(c0n);
  }
  __syncthreads();
  xh[rr][j] = h0n; xh[rr][256+j] = h1p;
  __syncthreads();
  if (alive){
    v2f A0={exb[1024+j],0.f}, A1={exb[1280+j],0.f}, A2={exb[1536+j],0.f}, A3={exb[1792+j],0.f};
    #pragma unroll 8
    for (int k2=0;k2<256;k2++){
      v2f hp = *(const v2f*)&xh[rr][2*k2];
      uint4 w = WB[k2*256+j];
      A0 += hp*unpk(w.x); A1 += hp*unpk(w.y);
      A2 += hp*unpk(w.z); A3 += hp*unpk(w.w);
    }
    float a0=A0.x+A0.y, a1=A1.x+A1.y, a2=A2.x+A2.y, a3=A3.x+A3.y;
    float c1n = sigf(a1)*c1p + sigf(a0)*tanh_fast(a2);
    float h1n = sigf(a3)*tanh_fast(c1n);
    int o = row*256 + j;
    c0o[o]=c0n; h0o[o]=h0n; c1o[o]=c1n; h1o[o]=h1n;
  }
}

// ---------------- K6: out = h_exit @ wo + bo -----------------------------
__global__ __launch_bounds__(256) void k_out(
    const float* __restrict__ h1f, const int* __restrict__ exitIdx,
    const float* __restrict__ wo, const float* __restrict__ bo, float* __restrict__ out){
  __shared__ float hv[8][256];
  int tid = threadIdx.x;
  for (int i = tid; i < 2048; i += 256){
    int b = i >> 8, k = i & 255;
    hv[b][k] = h1f[(b*81 + exitIdx[b])*256 + k];
  }
  __syncthreads();
  int v = blockIdx.x*256 + tid;
  if (v >= 30000) return;
  float acc[8];
  #pragma unroll
  for (int b=0;b<8;b++) acc[b] = bo[v];
  for (int k=0;k<256;k++){
    float w = wo[k*30000 + v];
    #pragma unroll
    for (int b=0;b<8;b++) acc[b] = fmaf(hv[b][k], w, acc[b]);
  }
  #pragma unroll
  for (int b=0;b<8;b++) out[b*30000+v] = acc[b];
}

// ---------------- launch --------------------------------------------------
extern "C" void kernel_launch(void* const* d_in, const int* in_sizes, int n_in,
                              void* d_out, int out_size, void* d_ws, size_t ws_size,
                              hipStream_t stream){
  (void)in_sizes; (void)n_in; (void)out_size;
  const float* ne    = (const float*)d_in[0];
  const int*   exitI = (const int*)d_in[10];
  const float* stWx  = (const float*)d_in[12];
  const float* stb   = (const float*)d_in[14];
  const float* skWx  = (const float*)d_in[15];
  const float* skWh  = (const float*)d_in[16];
  const float* skb   = (const float*)d_in[17];
  const float* lnS   = (const float*)d_in[18];
  const float* lnB   = (const float*)d_in[19];
  const float* exWx  = (const float*)d_in[20];
  const float* exWh  = (const float*)d_in[21];
  const float* exb   = (const float*)d_in[22];
  const float* wk    = (const float*)d_in[23];
  const float* bk    = (const float*)d_in[24];
  const float* wsm   = (const float*)d_in[25];
  const float* bs    = (const float*)d_in[26];
  const float* w1    = (const float*)d_in[27];
  const float* wo    = (const float*)d_in[29];
  const float* bo    = (const float*)d_in[30];
  float* out = (float*)d_out;

  char* w = (char*)d_ws;
  size_t off = 0;
  auto alloc = [&](size_t bytes)->char*{
    char* p = w + off; off += (bytes + 255) & ~size_t(255); return p;
  };
  float4* X0   = (float4*)alloc((size_t)640*256*16);
  u32* W0p2    = (u32*)alloc((size_t)128*1024*4);    // diag(lnS_h0)*Wh0, bf16 packed
  u32* W1p2    = (u32*)alloc((size_t)256*1024*4);    // [Wx1 ; diag(lnS_h1)*Wh1]
  u32* WApk    = (u32*)alloc((size_t)256*1024*4);
  u32* WBpk    = (u32*)alloc((size_t)256*1024*4);
  u32* wkp     = (u32*)alloc((size_t)512*256*4);
  u32* wspk    = (u32*)alloc((size_t)128*256*4);
  float* uv    = (float*)alloc((size_t)5120*4);
  float* skip  = (float*)alloc((size_t)8*81*81*256*4);   // fp32
  u16* keys    = (u16*)alloc((size_t)8*81*81*256*2);     // bf16
  float* tb    = (float*)alloc((size_t)ROWS*81*4);
  float* p0    = (float*)alloc(ROWS*4);
  float* p1    = (float*)alloc(ROWS*4);
  float* stA   = (float*)alloc((size_t)4*ROWS*256*4);
  float* stB   = (float*)alloc((size_t)4*ROWS*256*4);
  float* H0a   = (float*)alloc((size_t)640*256*4);
  float* H0b   = (float*)alloc((size_t)640*256*4);
  float* H1a   = (float*)alloc((size_t)640*256*4);
  float* H1b   = (float*)alloc((size_t)640*256*4);
  float* C0    = (float*)alloc((size_t)640*256*4);
  float* C1    = (float*)alloc((size_t)640*256*4);
  float* stats = (float*)alloc((size_t)80*640*2*4);
  if (off > ws_size) return;   // workspace too small — surfaces as absmax fail

  const size_t ST = (size_t)ROWS*256;
  float *A_c0=stA, *A_h0=stA+ST, *A_c1=stA+2*ST, *A_h1=stA+3*ST;
  float *B_c0=stB, *B_h0=stB+ST, *B_c1=stB+2*ST, *B_h1=stB+3*ST;

  hipMemsetAsync(skip, 0, (size_t)8*81*81*256*4, stream);
  hipMemsetAsync(stats, 0, (size_t)80*640*2*4, stream);
  hipMemsetAsync(stA, 0, (size_t)4*ROWS*256*4, stream);
  hipMemsetAsync(stB, 0, (size_t)4*ROWS*256*4, stream);
  k_init_p<<<3,256,0,stream>>>(p0);

  pack_gates_sc<<<512, 256, 0, stream>>>(skWh, skWh, lnS+256, nullptr, W0p2, 256);
  pack_gates_sc<<<1024,256, 0, stream>>>(skWx+256*1024, skWh+256*1024, nullptr, lnS+768, W1p2, 512);
  pack_gates<<<1024,256, 0, stream>>>(exWx, exWh, WApk, 512);
  pack_gates<<<1024,256, 0, stream>>>(exWx+256*1024, exWh+256*1024, WBpk, 512);
  pack_pairs<<<512, 256, 0, stream>>>(wk, wkp, 512, 256);
  pack_pairs<<<128, 256, 0, stream>>>(wsm, wspk, 128, 256);
  k_uv<<<4, 256, 0, stream>>>(skWh, skWh+256*1024, lnS, lnB, skb, uv);

  k_stmt_x0<<<320, 512, 0, stream>>>(ne, stWx, stb, skWx, skb, X0);

  // wavefront: 80 global steps, 2 phases each
  for (int idx=0; idx<80; idx++){
    float* H0in  = (idx&1) ? H0a : H0b;
    float* H0out = (idx&1) ? H0b : H0a;
    float* H1in  = (idx&1) ? H1a : H1b;
    float* H1out = (idx&1) ? H1b : H1a;
    dim3 gw(idx+1, 8);
    k_wf0<<<gw, 256, 0, stream>>>(X0, (const uint4*)W0p2, (const float4*)uv,
                                  H0in, H0out, C0, stats, lnS, lnB, idx);
    k_wf1<<<gw, 256, 0, stream>>>((const uint4*)W1p2, (const float4*)uv,
                                  H0out, H1in, H1out, C1, C0, skip, stats, lnS, lnB, idx);
  }

  k_keys<<<648, 256, 0, stream>>>(skip, wspk, bs, keys);

  float* pc = p0; float* pn = p1;
  for (int s=0; s<8; s++){
    float *ic0,*ih0,*ic1,*ih1,*oc0,*oh0,*oc1,*oh1;
    if ((s & 1) == 0){ ic0=A_c0; ih0=A_h0; ic1=A_c1; ih1=A_h1; oc0=B_c0; oh0=B_h0; oc1=B_c1; oh1=B_h1; }
    else             { ic0=B_c0; ih0=B_h0; ic1=B_c1; ih1=B_h1; oc0=A_c0; oh0=A_h0; oc1=A_c1; oh1=A_h1; }
    int mode = (s==0) ? 0 : ((s==7) ? 2 : 1);
    k_attn<<<648, 256, 0, stream>>>(ic0, ih0, ic1, ih1, wkp, bk, keys, w1, pc, tb, mode);
    k_update<<<162, 1024, 0, stream>>>(tb, skip, ic0, ih0, ic1, ih1,
                                       (const uint4*)WApk, (const uint4*)WBpk, exb,
                                       oc0, oh0, oc1, oh1, pn);
    float* tmp = pc; pc = pn; pn = tmp;
  }
  // final states are in buffer A (step 7 writes A)
  k_out<<<(30000+255)/256, 256, 0, stream>>>(A_h1, exitI, wo, bo, out);
}